// Round 5
// baseline (158.743 us; speedup 1.0000x reference)
//
#include <hip/hip_runtime.h>

typedef unsigned short u16;
typedef unsigned int u32;
typedef __attribute__((ext_vector_type(8))) short short8;
typedef __attribute__((ext_vector_type(4))) float f32x4;

__device__ __forceinline__ float bf2f(u16 h){ return __builtin_bit_cast(float, ((u32)h) << 16); }
__device__ __forceinline__ u16 f2bf(float f){
  u32 u = __builtin_bit_cast(u32, f);
  u32 r = u + 0x7fffu + ((u >> 16) & 1u);
  return (u16)(r >> 16);
}
// byte offset of channel-octet `co` of tile-pixel `px` in a swizzled [px][256ch] bf16 LDS tile
__device__ __forceinline__ int swzb(int px, int co){
  return px * 512 + ((co * 16) ^ ((((px & 7) ^ ((px >> 3) * 3)) & 7) << 4));
}

// ------- Kernel 0: x fp32 [b][c][hw] -> XTh/XTl bf16 hi/lo split, pixel-major [pix][c] -------
__global__ __launch_bounds__(256) void split_in(const float* __restrict__ x,
                                                u16* __restrict__ XTh,
                                                u16* __restrict__ XTl)
{
  __shared__ float tile[64 * 68];
  int t = threadIdx.x;
  int hw0 = blockIdx.x * 64, c0 = blockIdx.y * 64, b = blockIdx.z;
  {
    int cl = t >> 2, seg = (t & 3) * 16;
    const float* src = x + (b * 256 + c0 + cl) * 4096 + hw0 + seg;
    float4 v0 = ((const float4*)src)[0];
    float4 v1 = ((const float4*)src)[1];
    float4 v2 = ((const float4*)src)[2];
    float4 v3 = ((const float4*)src)[3];
    float* d = tile + cl * 68 + seg;
    ((float4*)d)[0] = v0; ((float4*)d)[1] = v1;
    ((float4*)d)[2] = v2; ((float4*)d)[3] = v3;
  }
  __syncthreads();
  {
    int hwl = t >> 2, cs = (t & 3) * 16;
    u32 ph[8], pl[8];
    #pragma unroll
    for (int e = 0; e < 8; ++e) {
      float v0 = tile[(cs + 2 * e) * 68 + hwl];
      float v1 = tile[(cs + 2 * e + 1) * 68 + hwl];
      u16 h0 = f2bf(v0), h1 = f2bf(v1);
      u16 l0 = f2bf(v0 - bf2f(h0)), l1 = f2bf(v1 - bf2f(h1));
      ph[e] = (u32)h0 | ((u32)h1 << 16);
      pl[e] = (u32)l0 | ((u32)l1 << 16);
    }
    int off = (b * 4096 + hw0 + hwl) * 256 + c0 + cs;
    *(uint4*)(XTh + off)     = make_uint4(ph[0], ph[1], ph[2], ph[3]);
    *(uint4*)(XTh + off + 8) = make_uint4(ph[4], ph[5], ph[6], ph[7]);
    *(uint4*)(XTl + off)     = make_uint4(pl[0], pl[1], pl[2], pl[3]);
    *(uint4*)(XTl + off + 8) = make_uint4(pl[4], pl[5], pl[6], pl[7]);
  }
}

// ------- Kernel 0b: w1|w2|w3 fp32 [o][c] -> Wh/Wl bf16 hi/lo -------
__global__ __launch_bounds__(256) void wsplit(const float* __restrict__ w1,
                                              const float* __restrict__ w2,
                                              const float* __restrict__ w3,
                                              u16* __restrict__ Wh,
                                              u16* __restrict__ Wl)
{
  int i = (blockIdx.x * 256 + threadIdx.x) * 4;
  int z = i >> 16, off = i & 65535;
  const float* w = (z == 0) ? w1 : ((z == 1) ? w2 : w3);
  float4 v = *(const float4*)(w + off);
  u16 h0 = f2bf(v.x), h1 = f2bf(v.y), h2 = f2bf(v.z), h3 = f2bf(v.w);
  u16 l0 = f2bf(v.x - bf2f(h0)), l1 = f2bf(v.y - bf2f(h1));
  u16 l2 = f2bf(v.z - bf2f(h2)), l3 = f2bf(v.w - bf2f(h3));
  uint2 hv; hv.x = (u32)h0 | ((u32)h1 << 16); hv.y = (u32)h2 | ((u32)h3 << 16);
  uint2 lv; lv.x = (u32)l0 | ((u32)l1 << 16); lv.y = (u32)l2 | ((u32)l3 << 16);
  *(uint2*)(Wh + i) = hv;
  *(uint2*)(Wl + i) = lv;
}

// ------- Kernel 1 (rewritten): fused qkv. One block = 64 pixels x 256 outputs x all z.
// A (x hi/lo, 64 KB) staged ONCE in swzb layout, reused across 24 K-steps.
// B (weights) double-buffered 16 KB tiles via global_load_lds w/ source-chunk XOR (R4 pattern).
// Per wave per K-step: 16 n-tiles x {hh,hl,lh} MFMA (z<2) into 16 f32x4 acc.
// Epilogue: acc -> flat LDS tile -> fully-coalesced uint4 stores. Bit-identical numerics.
// grid 256 = 1 block/CU (128 KB LDS). -------
__global__ __launch_bounds__(256) void qkv_gemm(const u16* __restrict__ XTh,
                                                const u16* __restrict__ XTl,
                                                const u16* __restrict__ Wh,
                                                const u16* __restrict__ Wl,
                                                u16* __restrict__ qh_, u16* __restrict__ ql_,
                                                u16* __restrict__ kh_, u16* __restrict__ kl_,
                                                u16* __restrict__ vo)
{
  __shared__ u16 lA[32768];   // 64 KB: A hi [0..16383], A lo [16384..32767], swzb [64px][256ch]
  __shared__ u16 lBs[32768];  // 64 KB: buf0 hi @0, buf0 lo @8192, buf1 hi @16384, buf1 lo @24576
  const int t = threadIdx.x;
  const int lane = t & 63, wv = t >> 6;
  const int l15 = lane & 15, q4 = lane >> 4;
  const int pix0 = blockIdx.x * 64;
  char* lAc = (char*)lA;

  const int qsw = (q4 ^ ((l15 >> 1) & 3)) * 8;          // read-side B chunk swizzle (u16)
  const int Lr = lane >> 2;                             // staging row-in-slice
  const int cswz = (lane & 3) ^ ((lane >> 3) & 3);      // staging source-chunk XOR (involution)

  // ---- A stage (once): register path into swzb layout ----
  #pragma unroll
  for (int it = 0; it < 8; ++it) {
    const int s = t + it * 256;                         // 0..2047
    const int px = s >> 5, co = s & 31;
    const int g = (pix0 + px) * 256 + co * 8;
    const uint4 vh = *(const uint4*)(XTh + g);
    const uint4 vl = *(const uint4*)(XTl + g);
    const int off = swzb(px, co);
    *(uint4*)(lAc + off) = vh;
    *(uint4*)(lAc + 32768 + off) = vl;
  }

  for (int z = 0; z < 3; ++z) {
    const u16* WhZ = Wh + z * 65536;
    const u16* WlZ = Wl + z * 65536;
    f32x4 acc[16];
    #pragma unroll
    for (int nt = 0; nt < 16; ++nt) acc[nt] = (f32x4){0.f, 0.f, 0.f, 0.f};

    __syncthreads();   // z=0: A-stage done; z>0: epilogue LDS reads done -> lBs reusable
    // stage B(z, kc=0) -> buf0
    #pragma unroll
    for (int it = 0; it < 4; ++it) {
      const int row = wv * 64 + it * 16 + Lr;
      u16* dst = lBs + (wv * 64 + it * 16) * 32;        // wave-uniform slice base
      __builtin_amdgcn_global_load_lds((const u32*)(WhZ + row * 256 + cswz * 8), (u32*)dst, 16, 0, 0);
      if (z < 2)
        __builtin_amdgcn_global_load_lds((const u32*)(WlZ + row * 256 + cswz * 8), (u32*)(dst + 8192), 16, 0, 0);
    }
    __syncthreads();   // buf0 visible

    int cur = 0;
    for (int kc8 = 0; kc8 < 8; ++kc8) {
      if (kc8 < 7) {   // prefetch next K-slice into the other buffer (lands during compute)
        const int nb = cur ^ 1;
        #pragma unroll
        for (int it = 0; it < 4; ++it) {
          const int row = wv * 64 + it * 16 + Lr;
          u16* dst = lBs + nb * 16384 + (wv * 64 + it * 16) * 32;
          __builtin_amdgcn_global_load_lds((const u32*)(WhZ + row * 256 + (kc8 + 1) * 32 + cswz * 8), (u32*)dst, 16, 0, 0);
          if (z < 2)
            __builtin_amdgcn_global_load_lds((const u32*)(WlZ + row * 256 + (kc8 + 1) * 32 + cswz * 8), (u32*)(dst + 8192), 16, 0, 0);
        }
      }
      const u16* bufH = lBs + cur * 16384;
      const u16* bufL = bufH + 8192;
      const int aoff = swzb(wv * 16 + l15, kc8 * 4 + q4);
      const short8 ah = *(const short8*)(lAc + aoff);
      const short8 al = *(const short8*)(lAc + 32768 + aoff);
      #pragma unroll
      for (int nt = 0; nt < 16; ++nt) {
        const short8 bh = *(const short8*)(bufH + (nt * 16 + l15) * 32 + qsw);
        acc[nt] = __builtin_amdgcn_mfma_f32_16x16x32_bf16(ah, bh, acc[nt], 0, 0, 0);
        if (z < 2) {
          const short8 bl = *(const short8*)(bufL + (nt * 16 + l15) * 32 + qsw);
          acc[nt] = __builtin_amdgcn_mfma_f32_16x16x32_bf16(ah, bl, acc[nt], 0, 0, 0);
          acc[nt] = __builtin_amdgcn_mfma_f32_16x16x32_bf16(al, bh, acc[nt], 0, 0, 0);
        }
      }
      __syncthreads();  // all waves done reading cur; prefetch drained (vmcnt 0 at barrier)
      cur ^= 1;
    }

    // ---- epilogue: acc -> flat LDS [64px][256o] -> coalesced 16B global stores ----
    // D mapping: row m = q4*4+r (pixel within wave's 16-px tile), col n = nt*16 + l15 (o)
    u16* hiP = lBs;               // 16384 u16 (32 KB)
    u16* loP = lBs + 16384;
    if (z < 2) {
      #pragma unroll
      for (int nt = 0; nt < 16; ++nt)
        #pragma unroll
        for (int r = 0; r < 4; ++r) {
          const float vv = acc[nt][r];
          const u16 hh = f2bf(vv);
          const u16 ll = f2bf(vv - bf2f(hh));
          const int idx = (wv * 16 + q4 * 4 + r) * 256 + nt * 16 + l15;
          hiP[idx] = hh; loP[idx] = ll;
        }
      __syncthreads();
      u16* dsth = (z == 0) ? qh_ : kh_;
      u16* dstl = (z == 0) ? ql_ : kl_;
      #pragma unroll
      for (int it = 0; it < 8; ++it) {
        const int s = t + it * 256;
        *(uint4*)(dsth + pix0 * 256 + s * 8) = *(const uint4*)(hiP + s * 8);
        *(uint4*)(dstl + pix0 * 256 + s * 8) = *(const uint4*)(loP + s * 8);
      }
    } else {
      #pragma unroll
      for (int nt = 0; nt < 16; ++nt)
        #pragma unroll
        for (int r = 0; r < 4; ++r) {
          const int idx = (wv * 16 + q4 * 4 + r) * 256 + nt * 16 + l15;
          hiP[idx] = f2bf(acc[nt][r]);
        }
      __syncthreads();
      #pragma unroll
      for (int it = 0; it < 8; ++it) {
        const int s = t + it * 256;
        *(uint4*)(vo + pix0 * 256 + s * 8) = *(const uint4*)(hiP + s * 8);
      }
    }
  }
}

// ------- Kernel 2: banded-MFMA local attention (unchanged from R3/R4). -------
__global__ __launch_bounds__(256, 4) void attn(const u16* __restrict__ qh_,
                                               const u16* __restrict__ ql_,
                                               const u16* __restrict__ kh_,
                                               const u16* __restrict__ kl_,
                                               const u16* __restrict__ vo,
                                               float* __restrict__ out)
{
  __shared__ u16 kst[12288];             // 24576 B: k hi @0, k lo @+12288B; q hi @0/lo @+8192B; v @0 (16 KB)
  __shared__ float lg2[2][16][57];       // 7296 B
  __shared__ u16 pb[7][16][40];          // 8960 B   (total 40832 <= 40960 -> 4 blocks/CU)

  const int t = threadIdx.x;
  const int lane = t & 63, wv = t >> 6;
  const int l15 = lane & 15, q4 = lane >> 4;
  const int bid = ((int)blockIdx.x & 7) * 128 + ((int)blockIdx.x >> 3);  // XCD-bijective
  const int quarter = bid & 3;
  const int row = bid >> 2;               // b*64 + h
  const int b = row >> 6, h = row & 63;
  const int wbase = quarter * 16;
  char* sk = (char*)kst;

  for (int i = t; i < 2 * 16 * 57; i += 256) ((float*)lg2)[i] = 0.f;
  for (int i = t; i < 2240; i += 256) ((u32*)pb)[i] = 0u;

  // ---------- q stage (coalesced 16 KB) ----------
  #pragma unroll
  for (int it = 0; it < 2; ++it) {
    const int s = t + it * 256;                 // 0..511
    const int px = s >> 5, co = s & 31;
    const int g = (row * 64 + wbase + px) * 256 + co * 8;
    const uint4 vh = *(const uint4*)(qh_ + g);
    const uint4 vl = *(const uint4*)(ql_ + g);
    const int off = swzb(px, co);
    *(uint4*)(sk + off) = vh;
    *(uint4*)(sk + 8192 + off) = vl;
  }

  const int ch = wv >> 1, win = wv & 1;          // wave -> (c-half, n-window)
  uint4 ph[3], pl[3];
  // k prefetch for dh=0 (flies during barrier + q-frag reads)
  {
    const int rdh0 = h - 3;
    const int rdhc = rdh0 < 0 ? 0 : rdh0;
    const int rp = (b * 64 + rdhc) * 64;
    #pragma unroll
    for (int it = 0; it < 3; ++it) {
      const int s = t + it * 256;
      const int px = s >> 5, co = s & 31;
      const int w = wbase - 4 + px;
      const int wc = w < 0 ? 0 : (w > 63 ? 63 : w);
      const int g = (rp + wc) * 256 + co * 8;
      uint4 vh = *(const uint4*)(kh_ + g);
      uint4 vl = *(const uint4*)(kl_ + g);
      const bool zz = (w < 0) | (w > 63);
      ph[it].x = zz ? 0u : vh.x; ph[it].y = zz ? 0u : vh.y; ph[it].z = zz ? 0u : vh.z; ph[it].w = zz ? 0u : vh.w;
      pl[it].x = zz ? 0u : vl.x; pl[it].y = zz ? 0u : vl.y; pl[it].z = zz ? 0u : vl.z; pl[it].w = zz ? 0u : vl.w;
    }
  }
  __syncthreads();

  // q fragments from LDS
  short8 qfh[4], qfl[4];
  #pragma unroll
  for (int u = 0; u < 4; ++u) {
    const int co = (ch * 4 + u) * 4 + q4;
    const int off = swzb(l15, co);
    qfh[u] = *(const short8*)(sk + off);
    qfl[u] = *(const short8*)(sk + 8192 + off);
  }

  // ---------- phase 1: logits ----------
  const int tidx = win ? (l15 + 12 > 23 ? 23 : l15 + 12) : (l15 - 4 < 0 ? 0 : l15 - 4);
  #pragma unroll 1
  for (int dh = 0; dh < 7; ++dh) {
    __syncthreads();                      // previous compute done reading kst
    #pragma unroll
    for (int it = 0; it < 3; ++it) {      // WRITEK
      const int s = t + it * 256;
      const int px = s >> 5, co = s & 31;
      const int off = swzb(px, co);
      *(uint4*)(sk + off) = ph[it];
      *(uint4*)(sk + 12288 + off) = pl[it];
    }
    if (dh < 6) {                         // LOADK(dh+1): flies during compute
      const int rdh1 = h + dh - 2;
      const int rdhc = rdh1 < 0 ? 0 : (rdh1 > 63 ? 63 : rdh1);
      const int rp = (b * 64 + rdhc) * 64;
      #pragma unroll
      for (int it = 0; it < 3; ++it) {
        const int s = t + it * 256;
        const int px = s >> 5, co = s & 31;
        const int w = wbase - 4 + px;
        const int wc = w < 0 ? 0 : (w > 63 ? 63 : w);
        const int g = (rp + wc) * 256 + co * 8;
        uint4 vh = *(const uint4*)(kh_ + g);
        uint4 vl = *(const uint4*)(kl_ + g);
        const bool zz = (w < 0) | (w > 63);
        ph[it].x = zz ? 0u : vh.x; ph[it].y = zz ? 0u : vh.y; ph[it].z = zz ? 0u : vh.z; ph[it].w = zz ? 0u : vh.w;
        pl[it].x = zz ? 0u : vl.x; pl[it].y = zz ? 0u : vl.y; pl[it].z = zz ? 0u : vl.z; pl[it].w = zz ? 0u : vl.w;
      }
    }
    __syncthreads();                      // staged tile visible
    const int rdh = h + dh - 3;
    const bool rok = (rdh >= 0) && (rdh < 64);
    f32x4 a0 = {0.f, 0.f, 0.f, 0.f};
    f32x4 a1 = {0.f, 0.f, 0.f, 0.f};     // split chains for MFMA ILP
    #pragma unroll
    for (int u = 0; u < 4; ++u) {
      const int co = (ch * 4 + u) * 4 + q4;
      const int off = swzb(tidx, co);
      const short8 bh_ = *(const short8*)(sk + off);
      const short8 bl_ = *(const short8*)(sk + 12288 + off);
      a0 = __builtin_amdgcn_mfma_f32_16x16x32_bf16(qfh[u], bh_, a0, 0, 0, 0);
      a1 = __builtin_amdgcn_mfma_f32_16x16x32_bf16(qfh[u], bl_, a1, 0, 0, 0);
      a0 = __builtin_amdgcn_mfma_f32_16x16x32_bf16(qfl[u], bh_, a0, 0, 0, 0);
    }
    // scatter band entries: D col n=l15, row m=q4*4+r; dw = n_w - m_w + 3
    #pragma unroll
    for (int r = 0; r < 4; ++r) {
      const int mloc = q4 * 4 + r;
      const int dw = l15 - mloc - 5 + win * 16;
      if (rok && dw >= 0 && dw < 7) lg2[ch][mloc][dh * 7 + dw] = a0[r] + a1[r];
    }
  }

  // v prefetch for dh=0 (flies during softmax)
  uint4 pv[4];
  {
    const int rdh0 = h - 3;
    const bool rok2 = rdh0 >= 0;
    const int rdhc = rdh0 < 0 ? 0 : rdh0;
    const int rp = (b * 64 + rdhc) * 64;
    #pragma unroll
    for (int it = 0; it < 4; ++it) {
      const int s = t + it * 256;
      const int px = s >> 5, co = s & 31;
      const int w = wbase - 8 + px;
      const int wc = w < 0 ? 0 : (w > 63 ? 63 : w);
      const int g = (rp + wc) * 256 + co * 8;
      uint4 vv = *(const uint4*)(vo + g);
      const bool zz = (!rok2) | (w < 0) | (w > 63);
      pv[it].x = zz ? 0u : vv.x; pv[it].y = zz ? 0u : vv.y; pv[it].z = zz ? 0u : vv.z; pv[it].w = zz ? 0u : vv.w;
    }
  }
  __syncthreads();

  // ---------- softmax: 16 lanes per pixel ----------
  {
    const int px = t >> 4, sub = t & 15;
    float mx = -3.0e38f;
    for (int i = sub; i < 49; i += 16)
      mx = fmaxf(mx, lg2[0][px][i] + lg2[1][px][i]);
    mx = fmaxf(mx, __shfl_xor(mx, 1));
    mx = fmaxf(mx, __shfl_xor(mx, 2));
    mx = fmaxf(mx, __shfl_xor(mx, 4));
    mx = fmaxf(mx, __shfl_xor(mx, 8));
    float s = 0.f;
    for (int i = sub; i < 49; i += 16) {
      float v = __expf(lg2[0][px][i] + lg2[1][px][i] - mx);
      lg2[0][px][i] = v;                  // stash exp (same-lane RAW only)
      s += v;
    }
    s += __shfl_xor(s, 1);
    s += __shfl_xor(s, 2);
    s += __shfl_xor(s, 4);
    s += __shfl_xor(s, 8);
    const float inv = 1.f / s;
    for (int i = sub; i < 49; i += 16) {
      const int dh7 = i / 7, dw7 = i - dh7 * 7;
      pb[dh7][px][px + 5 + dw7] = f2bf(lg2[0][px][i] * inv);
    }
  }

  // ---------- phase 2: out[c][m'] = sum_n' v[c][n'] * P[m'][n'] ----------
  f32x4 acc[4];
  #pragma unroll
  for (int i = 0; i < 4; ++i) acc[i] = (f32x4){0.f, 0.f, 0.f, 0.f};
  #pragma unroll 1
  for (int dh = 0; dh < 7; ++dh) {
    __syncthreads();                      // kst free (phase1 / prev iter done)
    #pragma unroll
    for (int it = 0; it < 4; ++it) {      // WRITEV
      const int s = t + it * 256;
      const int px = s >> 5, co = s & 31;
      *(uint4*)(sk + swzb(px, co)) = pv[it];
    }
    if (dh < 6) {                         // LOADV(dh+1)
      const int rdh1 = h + dh - 2;
      const bool rok2 = (rdh1 >= 0) && (rdh1 < 64);
      const int rdhc = rdh1 < 0 ? 0 : (rdh1 > 63 ? 63 : rdh1);
      const int rp = (b * 64 + rdhc) * 64;
      #pragma unroll
      for (int it = 0; it < 4; ++it) {
        const int s = t + it * 256;
        const int px = s >> 5, co = s & 31;
        const int w = wbase - 8 + px;
        const int wc = w < 0 ? 0 : (w > 63 ? 63 : w);
        const int g = (rp + wc) * 256 + co * 8;
        uint4 vv = *(const uint4*)(vo + g);
        const bool zz = (!rok2) | (w < 0) | (w > 63);
        pv[it].x = zz ? 0u : vv.x; pv[it].y = zz ? 0u : vv.y; pv[it].z = zz ? 0u : vv.z; pv[it].w = zz ? 0u : vv.w;
      }
    }
    __syncthreads();                      // tile visible
    #pragma unroll
    for (int i = 0; i < 4; ++i) {
      const int c = wv * 64 + i * 16 + l15;      // A: m = channel
      short8 af;
      u16* afp = (u16*)&af;
      #pragma unroll
      for (int e = 0; e < 8; ++e) {              // gather transpose from LDS
        const int px = q4 * 8 + e;               // k-dim = neighbor pixel
        const int off = swzb(px, c >> 3) + (c & 7) * 2;
        afp[e] = *(const u16*)(sk + off);
      }
      const short8 bf_ = *(const short8*)(&pb[dh][l15][q4 * 8]);
      acc[i] = __builtin_amdgcn_mfma_f32_16x16x32_bf16(af, bf_, acc[i], 0, 0, 0);
    }
  }
  #pragma unroll
  for (int i = 0; i < 4; ++i) {
    const int ct = wv * 4 + i;
    // D: row m = channel q4*4+r, col n = pixel l15 -> native [b][c][h][w]
    #pragma unroll
    for (int r = 0; r < 4; ++r)
      out[(b * 256 + ct * 16 + q4 * 4 + r) * 4096 + h * 64 + wbase + l15] = acc[i][r];
  }
}

extern "C" void kernel_launch(void* const* d_in, const int* in_sizes, int n_in,
                              void* d_out, int out_size, void* d_ws, size_t ws_size,
                              hipStream_t stream)
{
  const float* x  = (const float*)d_in[0];
  const float* w1 = (const float*)d_in[1];
  const float* w2 = (const float*)d_in[2];
  const float* w3 = (const float*)d_in[3];
  float* out = (float*)d_out;

  // x hi/lo bf16 split lives in d_out (16 MB); consumed by qkv_gemm, then d_out is
  // fully rewritten by attn phase 2 (stream-ordered).
  u16* XTh = (u16*)d_out;
  u16* XTl = XTh + 4194304;

  char* ws = (char*)d_ws;
  u16* qh_ = (u16*)ws;                     // 8 MB bf16 hi(q), pixel-major [pix][c]
  u16* ql_ = (u16*)(ws + (8u  << 20));     // 8 MB bf16 lo(q)
  u16* kh_ = (u16*)(ws + (16u << 20));     // 8 MB bf16 hi(k)
  u16* kl_ = (u16*)(ws + (24u << 20));     // 8 MB bf16 lo(k)
  u16* vo  = (u16*)(ws + (32u << 20));     // 8 MB bf16 v, pixel-major [pix][c]
  u16* Wh  = (u16*)(ws + (40u << 20));     // 384 KB
  u16* Wl  = Wh + 196608;                  // 384 KB

  split_in<<<dim3(64, 4, 4), 256, 0, stream>>>(x, XTh, XTl);
  wsplit<<<192, 256, 0, stream>>>(w1, w2, w3, Wh, Wl);
  qkv_gemm<<<dim3(256), 256, 0, stream>>>(XTh, XTl, Wh, Wl, qh_, ql_, kh_, kl_, vo);
  attn<<<dim3(1024), 256, 0, stream>>>(qh_, ql_, kh_, kl_, vo, out);
}

// Round 6
// 140.191 us; speedup vs baseline: 1.1323x; 1.1323x over previous
//
#include <hip/hip_runtime.h>

typedef unsigned short u16;
typedef unsigned int u32;
typedef __attribute__((ext_vector_type(8))) short short8;
typedef __attribute__((ext_vector_type(4))) float f32x4;

__device__ __forceinline__ float bf2f(u16 h){ return __builtin_bit_cast(float, ((u32)h) << 16); }
__device__ __forceinline__ u16 f2bf(float f){
  u32 u = __builtin_bit_cast(u32, f);
  u32 r = u + 0x7fffu + ((u >> 16) & 1u);
  return (u16)(r >> 16);
}
// byte offset of channel-octet `co` of tile-pixel `px` in a swizzled [px][256ch] bf16 LDS tile
__device__ __forceinline__ int swzb(int px, int co){
  return px * 512 + ((co * 16) ^ ((((px & 7) ^ ((px >> 3) * 3)) & 7) << 4));
}

// ------- Kernel 0: x fp32 [b][c][hw] -> XTh/XTl bf16 hi/lo split, pixel-major [pix][c] -------
__global__ __launch_bounds__(256) void split_in(const float* __restrict__ x,
                                                u16* __restrict__ XTh,
                                                u16* __restrict__ XTl)
{
  __shared__ float tile[64 * 68];
  int t = threadIdx.x;
  int hw0 = blockIdx.x * 64, c0 = blockIdx.y * 64, b = blockIdx.z;
  {
    int cl = t >> 2, seg = (t & 3) * 16;
    const float* src = x + (b * 256 + c0 + cl) * 4096 + hw0 + seg;
    float4 v0 = ((const float4*)src)[0];
    float4 v1 = ((const float4*)src)[1];
    float4 v2 = ((const float4*)src)[2];
    float4 v3 = ((const float4*)src)[3];
    float* d = tile + cl * 68 + seg;
    ((float4*)d)[0] = v0; ((float4*)d)[1] = v1;
    ((float4*)d)[2] = v2; ((float4*)d)[3] = v3;
  }
  __syncthreads();
  {
    int hwl = t >> 2, cs = (t & 3) * 16;
    u32 ph[8], pl[8];
    #pragma unroll
    for (int e = 0; e < 8; ++e) {
      float v0 = tile[(cs + 2 * e) * 68 + hwl];
      float v1 = tile[(cs + 2 * e + 1) * 68 + hwl];
      u16 h0 = f2bf(v0), h1 = f2bf(v1);
      u16 l0 = f2bf(v0 - bf2f(h0)), l1 = f2bf(v1 - bf2f(h1));
      ph[e] = (u32)h0 | ((u32)h1 << 16);
      pl[e] = (u32)l0 | ((u32)l1 << 16);
    }
    int off = (b * 4096 + hw0 + hwl) * 256 + c0 + cs;
    *(uint4*)(XTh + off)     = make_uint4(ph[0], ph[1], ph[2], ph[3]);
    *(uint4*)(XTh + off + 8) = make_uint4(ph[4], ph[5], ph[6], ph[7]);
    *(uint4*)(XTl + off)     = make_uint4(pl[0], pl[1], pl[2], pl[3]);
    *(uint4*)(XTl + off + 8) = make_uint4(pl[4], pl[5], pl[6], pl[7]);
  }
}

// ------- Kernel 0b: w1|w2|w3 fp32 [o][c] -> Wh/Wl bf16 hi/lo -------
__global__ __launch_bounds__(256) void wsplit(const float* __restrict__ w1,
                                              const float* __restrict__ w2,
                                              const float* __restrict__ w3,
                                              u16* __restrict__ Wh,
                                              u16* __restrict__ Wl)
{
  int i = (blockIdx.x * 256 + threadIdx.x) * 4;
  int z = i >> 16, off = i & 65535;
  const float* w = (z == 0) ? w1 : ((z == 1) ? w2 : w3);
  float4 v = *(const float4*)(w + off);
  u16 h0 = f2bf(v.x), h1 = f2bf(v.y), h2 = f2bf(v.z), h3 = f2bf(v.w);
  u16 l0 = f2bf(v.x - bf2f(h0)), l1 = f2bf(v.y - bf2f(h1));
  u16 l2 = f2bf(v.z - bf2f(h2)), l3 = f2bf(v.w - bf2f(h3));
  uint2 hv; hv.x = (u32)h0 | ((u32)h1 << 16); hv.y = (u32)h2 | ((u32)h3 << 16);
  uint2 lv; lv.x = (u32)l0 | ((u32)l1 << 16); lv.y = (u32)l2 | ((u32)l3 << 16);
  *(uint2*)(Wh + i) = hv;
  *(uint2*)(Wl + i) = lv;
}

// ------- Kernel 1: fused qkv, 1024 threads (16 waves -> 4 waves/SIMD, vs R5's 1).
// One block = 64 pixels x 256 outputs x all z. A (x hi/lo, 64 KB) staged ONCE, reused
// across 24 K-steps. B double-buffered 16 KB K-slices via global_load_lds + source-chunk
// XOR involution. Wave = (pixel-quartile p4, n-group ng of 4 tiles); acc = 4 f32x4.
// Epilogue: acc -> flat LDS -> fully coalesced uint4 stores. Bit-identical numerics.
// grid 256 = 1 block/CU (128 KB LDS, 16 waves/CU). -------
__global__ __launch_bounds__(1024) void qkv_gemm(const u16* __restrict__ XTh,
                                                 const u16* __restrict__ XTl,
                                                 const u16* __restrict__ Wh,
                                                 const u16* __restrict__ Wl,
                                                 u16* __restrict__ qh_, u16* __restrict__ ql_,
                                                 u16* __restrict__ kh_, u16* __restrict__ kl_,
                                                 u16* __restrict__ vo)
{
  __shared__ u16 lA[32768];   // 64 KB: A hi (bytes [0,32K)), A lo (bytes [32K,64K)), swzb layout
  __shared__ u16 lBs[32768];  // 64 KB: buf0 hi @0, buf0 lo @+8192(u16), buf1 @+16384(u16)
  const int t = threadIdx.x;
  const int lane = t & 63, wv = t >> 6;          // wv in [0,16)
  const int l15 = lane & 15, q4 = lane >> 4;
  const int p4 = wv & 3;                         // pixel quartile (16 px)
  const int ng = wv >> 2;                        // n-group (4 tiles of 16 o)
  const int pix0 = blockIdx.x * 64;
  char* lAc = (char*)lA;

  const int qsw = (q4 ^ ((l15 >> 1) & 3)) * 8;          // read-side B chunk swizzle (u16)
  const int Lr = lane >> 2;                             // staging row-in-slice (16 rows/wave)
  const int cswz = (lane & 3) ^ ((lane >> 3) & 3);      // staging source-chunk XOR (involution)

  // ---- A stage (once): register path into swzb layout ----
  #pragma unroll
  for (int it = 0; it < 2; ++it) {
    const int s = t + it * 1024;                        // 0..2047
    const int px = s >> 5, co = s & 31;
    const int g = (pix0 + px) * 256 + co * 8;
    const uint4 vh = *(const uint4*)(XTh + g);
    const uint4 vl = *(const uint4*)(XTl + g);
    const int off = swzb(px, co);
    *(uint4*)(lAc + off) = vh;
    *(uint4*)(lAc + 32768 + off) = vl;
  }

  for (int z = 0; z < 3; ++z) {
    const u16* WhZ = Wh + z * 65536;
    const u16* WlZ = Wl + z * 65536;
    f32x4 acc[4];
    #pragma unroll
    for (int nt = 0; nt < 4; ++nt) acc[nt] = (f32x4){0.f, 0.f, 0.f, 0.f};

    __syncthreads();   // z=0: A-stage done; z>0: epilogue LDS reads done -> lBs reusable
    // stage B(z, kc=0) -> buf0: wave wv stages rows [wv*16, wv*16+16)
    {
      const int row = wv * 16 + Lr;
      u16* dst = lBs + (wv * 16) * 32;                  // wave-uniform slice base
      __builtin_amdgcn_global_load_lds((const u32*)(WhZ + row * 256 + cswz * 8), (u32*)dst, 16, 0, 0);
      if (z < 2)
        __builtin_amdgcn_global_load_lds((const u32*)(WlZ + row * 256 + cswz * 8), (u32*)(dst + 8192), 16, 0, 0);
    }
    __syncthreads();   // buf0 visible

    int cur = 0;
    for (int kc8 = 0; kc8 < 8; ++kc8) {
      if (kc8 < 7) {   // prefetch next K-slice into the other buffer (lands during compute)
        const int nb = cur ^ 1;
        const int row = wv * 16 + Lr;
        u16* dst = lBs + nb * 16384 + (wv * 16) * 32;
        __builtin_amdgcn_global_load_lds((const u32*)(WhZ + row * 256 + (kc8 + 1) * 32 + cswz * 8), (u32*)dst, 16, 0, 0);
        if (z < 2)
          __builtin_amdgcn_global_load_lds((const u32*)(WlZ + row * 256 + (kc8 + 1) * 32 + cswz * 8), (u32*)(dst + 8192), 16, 0, 0);
      }
      const u16* bufH = lBs + cur * 16384;
      const u16* bufL = bufH + 8192;
      const int aoff = swzb(p4 * 16 + l15, kc8 * 4 + q4);
      const short8 ah = *(const short8*)(lAc + aoff);
      short8 al;
      if (z < 2) al = *(const short8*)(lAc + 32768 + aoff);
      #pragma unroll
      for (int nt = 0; nt < 4; ++nt) {
        const int brow = (ng * 4 + nt) * 16 + l15;
        const short8 bh = *(const short8*)(bufH + brow * 32 + qsw);
        acc[nt] = __builtin_amdgcn_mfma_f32_16x16x32_bf16(ah, bh, acc[nt], 0, 0, 0);
        if (z < 2) {
          const short8 bl = *(const short8*)(bufL + brow * 32 + qsw);
          acc[nt] = __builtin_amdgcn_mfma_f32_16x16x32_bf16(ah, bl, acc[nt], 0, 0, 0);
          acc[nt] = __builtin_amdgcn_mfma_f32_16x16x32_bf16(al, bh, acc[nt], 0, 0, 0);
        }
      }
      __syncthreads();  // all waves done reading cur; prefetch drained (vmcnt 0 at barrier)
      cur ^= 1;
    }

    // ---- epilogue: acc -> flat LDS [64px][256o] -> coalesced 16B global stores ----
    // D mapping: pixel m = p4*16 + q4*4 + r, o n = (ng*4+nt)*16 + l15
    u16* hiP = lBs;               // 16384 u16 (32 KB)
    u16* loP = lBs + 16384;
    if (z < 2) {
      #pragma unroll
      for (int nt = 0; nt < 4; ++nt)
        #pragma unroll
        for (int r = 0; r < 4; ++r) {
          const float vv = acc[nt][r];
          const u16 hh = f2bf(vv);
          const u16 ll = f2bf(vv - bf2f(hh));
          const int idx = (p4 * 16 + q4 * 4 + r) * 256 + (ng * 4 + nt) * 16 + l15;
          hiP[idx] = hh; loP[idx] = ll;
        }
      __syncthreads();
      u16* dsth = (z == 0) ? qh_ : kh_;
      u16* dstl = (z == 0) ? ql_ : kl_;
      #pragma unroll
      for (int it = 0; it < 2; ++it) {
        const int s = t + it * 1024;
        *(uint4*)(dsth + pix0 * 256 + s * 8) = *(const uint4*)(hiP + s * 8);
        *(uint4*)(dstl + pix0 * 256 + s * 8) = *(const uint4*)(loP + s * 8);
      }
    } else {
      #pragma unroll
      for (int nt = 0; nt < 4; ++nt)
        #pragma unroll
        for (int r = 0; r < 4; ++r) {
          const int idx = (p4 * 16 + q4 * 4 + r) * 256 + (ng * 4 + nt) * 16 + l15;
          hiP[idx] = f2bf(acc[nt][r]);
        }
      __syncthreads();
      #pragma unroll
      for (int it = 0; it < 2; ++it) {
        const int s = t + it * 1024;
        *(uint4*)(vo + pix0 * 256 + s * 8) = *(const uint4*)(hiP + s * 8);
      }
    }
  }
}

// ------- Kernel 2: banded-MFMA local attention (unchanged from R3/R4). -------
__global__ __launch_bounds__(256, 4) void attn(const u16* __restrict__ qh_,
                                               const u16* __restrict__ ql_,
                                               const u16* __restrict__ kh_,
                                               const u16* __restrict__ kl_,
                                               const u16* __restrict__ vo,
                                               float* __restrict__ out)
{
  __shared__ u16 kst[12288];             // 24576 B: k hi @0, k lo @+12288B; q hi @0/lo @+8192B; v @0 (16 KB)
  __shared__ float lg2[2][16][57];       // 7296 B
  __shared__ u16 pb[7][16][40];          // 8960 B   (total 40832 <= 40960 -> 4 blocks/CU)

  const int t = threadIdx.x;
  const int lane = t & 63, wv = t >> 6;
  const int l15 = lane & 15, q4 = lane >> 4;
  const int bid = ((int)blockIdx.x & 7) * 128 + ((int)blockIdx.x >> 3);  // XCD-bijective
  const int quarter = bid & 3;
  const int row = bid >> 2;               // b*64 + h
  const int b = row >> 6, h = row & 63;
  const int wbase = quarter * 16;
  char* sk = (char*)kst;

  for (int i = t; i < 2 * 16 * 57; i += 256) ((float*)lg2)[i] = 0.f;
  for (int i = t; i < 2240; i += 256) ((u32*)pb)[i] = 0u;

  // ---------- q stage (coalesced 16 KB) ----------
  #pragma unroll
  for (int it = 0; it < 2; ++it) {
    const int s = t + it * 256;                 // 0..511
    const int px = s >> 5, co = s & 31;
    const int g = (row * 64 + wbase + px) * 256 + co * 8;
    const uint4 vh = *(const uint4*)(qh_ + g);
    const uint4 vl = *(const uint4*)(ql_ + g);
    const int off = swzb(px, co);
    *(uint4*)(sk + off) = vh;
    *(uint4*)(sk + 8192 + off) = vl;
  }

  const int ch = wv >> 1, win = wv & 1;          // wave -> (c-half, n-window)
  uint4 ph[3], pl[3];
  // k prefetch for dh=0 (flies during barrier + q-frag reads)
  {
    const int rdh0 = h - 3;
    const int rdhc = rdh0 < 0 ? 0 : rdh0;
    const int rp = (b * 64 + rdhc) * 64;
    #pragma unroll
    for (int it = 0; it < 3; ++it) {
      const int s = t + it * 256;
      const int px = s >> 5, co = s & 31;
      const int w = wbase - 4 + px;
      const int wc = w < 0 ? 0 : (w > 63 ? 63 : w);
      const int g = (rp + wc) * 256 + co * 8;
      uint4 vh = *(const uint4*)(kh_ + g);
      uint4 vl = *(const uint4*)(kl_ + g);
      const bool zz = (w < 0) | (w > 63);
      ph[it].x = zz ? 0u : vh.x; ph[it].y = zz ? 0u : vh.y; ph[it].z = zz ? 0u : vh.z; ph[it].w = zz ? 0u : vh.w;
      pl[it].x = zz ? 0u : vl.x; pl[it].y = zz ? 0u : vl.y; pl[it].z = zz ? 0u : vl.z; pl[it].w = zz ? 0u : vl.w;
    }
  }
  __syncthreads();

  // q fragments from LDS
  short8 qfh[4], qfl[4];
  #pragma unroll
  for (int u = 0; u < 4; ++u) {
    const int co = (ch * 4 + u) * 4 + q4;
    const int off = swzb(l15, co);
    qfh[u] = *(const short8*)(sk + off);
    qfl[u] = *(const short8*)(sk + 8192 + off);
  }

  // ---------- phase 1: logits ----------
  const int tidx = win ? (l15 + 12 > 23 ? 23 : l15 + 12) : (l15 - 4 < 0 ? 0 : l15 - 4);
  #pragma unroll 1
  for (int dh = 0; dh < 7; ++dh) {
    __syncthreads();                      // previous compute done reading kst
    #pragma unroll
    for (int it = 0; it < 3; ++it) {      // WRITEK
      const int s = t + it * 256;
      const int px = s >> 5, co = s & 31;
      const int off = swzb(px, co);
      *(uint4*)(sk + off) = ph[it];
      *(uint4*)(sk + 12288 + off) = pl[it];
    }
    if (dh < 6) {                         // LOADK(dh+1): flies during compute
      const int rdh1 = h + dh - 2;
      const int rdhc = rdh1 < 0 ? 0 : (rdh1 > 63 ? 63 : rdh1);
      const int rp = (b * 64 + rdhc) * 64;
      #pragma unroll
      for (int it = 0; it < 3; ++it) {
        const int s = t + it * 256;
        const int px = s >> 5, co = s & 31;
        const int w = wbase - 4 + px;
        const int wc = w < 0 ? 0 : (w > 63 ? 63 : w);
        const int g = (rp + wc) * 256 + co * 8;
        uint4 vh = *(const uint4*)(kh_ + g);
        uint4 vl = *(const uint4*)(kl_ + g);
        const bool zz = (w < 0) | (w > 63);
        ph[it].x = zz ? 0u : vh.x; ph[it].y = zz ? 0u : vh.y; ph[it].z = zz ? 0u : vh.z; ph[it].w = zz ? 0u : vh.w;
        pl[it].x = zz ? 0u : vl.x; pl[it].y = zz ? 0u : vl.y; pl[it].z = zz ? 0u : vl.z; pl[it].w = zz ? 0u : vl.w;
      }
    }
    __syncthreads();                      // staged tile visible
    const int rdh = h + dh - 3;
    const bool rok = (rdh >= 0) && (rdh < 64);
    f32x4 a0 = {0.f, 0.f, 0.f, 0.f};
    f32x4 a1 = {0.f, 0.f, 0.f, 0.f};     // split chains for MFMA ILP
    #pragma unroll
    for (int u = 0; u < 4; ++u) {
      const int co = (ch * 4 + u) * 4 + q4;
      const int off = swzb(tidx, co);
      const short8 bh_ = *(const short8*)(sk + off);
      const short8 bl_ = *(const short8*)(sk + 12288 + off);
      a0 = __builtin_amdgcn_mfma_f32_16x16x32_bf16(qfh[u], bh_, a0, 0, 0, 0);
      a1 = __builtin_amdgcn_mfma_f32_16x16x32_bf16(qfh[u], bl_, a1, 0, 0, 0);
      a0 = __builtin_amdgcn_mfma_f32_16x16x32_bf16(qfl[u], bh_, a0, 0, 0, 0);
    }
    // scatter band entries: D col n=l15, row m=q4*4+r; dw = n_w - m_w + 3
    #pragma unroll
    for (int r = 0; r < 4; ++r) {
      const int mloc = q4 * 4 + r;
      const int dw = l15 - mloc - 5 + win * 16;
      if (rok && dw >= 0 && dw < 7) lg2[ch][mloc][dh * 7 + dw] = a0[r] + a1[r];
    }
  }

  // v prefetch for dh=0 (flies during softmax)
  uint4 pv[4];
  {
    const int rdh0 = h - 3;
    const bool rok2 = rdh0 >= 0;
    const int rdhc = rdh0 < 0 ? 0 : rdh0;
    const int rp = (b * 64 + rdhc) * 64;
    #pragma unroll
    for (int it = 0; it < 4; ++it) {
      const int s = t + it * 256;
      const int px = s >> 5, co = s & 31;
      const int w = wbase - 8 + px;
      const int wc = w < 0 ? 0 : (w > 63 ? 63 : w);
      const int g = (rp + wc) * 256 + co * 8;
      uint4 vv = *(const uint4*)(vo + g);
      const bool zz = (!rok2) | (w < 0) | (w > 63);
      pv[it].x = zz ? 0u : vv.x; pv[it].y = zz ? 0u : vv.y; pv[it].z = zz ? 0u : vv.z; pv[it].w = zz ? 0u : vv.w;
    }
  }
  __syncthreads();

  // ---------- softmax: 16 lanes per pixel ----------
  {
    const int px = t >> 4, sub = t & 15;
    float mx = -3.0e38f;
    for (int i = sub; i < 49; i += 16)
      mx = fmaxf(mx, lg2[0][px][i] + lg2[1][px][i]);
    mx = fmaxf(mx, __shfl_xor(mx, 1));
    mx = fmaxf(mx, __shfl_xor(mx, 2));
    mx = fmaxf(mx, __shfl_xor(mx, 4));
    mx = fmaxf(mx, __shfl_xor(mx, 8));
    float s = 0.f;
    for (int i = sub; i < 49; i += 16) {
      float v = __expf(lg2[0][px][i] + lg2[1][px][i] - mx);
      lg2[0][px][i] = v;                  // stash exp (same-lane RAW only)
      s += v;
    }
    s += __shfl_xor(s, 1);
    s += __shfl_xor(s, 2);
    s += __shfl_xor(s, 4);
    s += __shfl_xor(s, 8);
    const float inv = 1.f / s;
    for (int i = sub; i < 49; i += 16) {
      const int dh7 = i / 7, dw7 = i - dh7 * 7;
      pb[dh7][px][px + 5 + dw7] = f2bf(lg2[0][px][i] * inv);
    }
  }

  // ---------- phase 2: out[c][m'] = sum_n' v[c][n'] * P[m'][n'] ----------
  f32x4 acc[4];
  #pragma unroll
  for (int i = 0; i < 4; ++i) acc[i] = (f32x4){0.f, 0.f, 0.f, 0.f};
  #pragma unroll 1
  for (int dh = 0; dh < 7; ++dh) {
    __syncthreads();                      // kst free (phase1 / prev iter done)
    #pragma unroll
    for (int it = 0; it < 4; ++it) {      // WRITEV
      const int s = t + it * 256;
      const int px = s >> 5, co = s & 31;
      *(uint4*)(sk + swzb(px, co)) = pv[it];
    }
    if (dh < 6) {                         // LOADV(dh+1)
      const int rdh1 = h + dh - 2;
      const bool rok2 = (rdh1 >= 0) && (rdh1 < 64);
      const int rdhc = rdh1 < 0 ? 0 : (rdh1 > 63 ? 63 : rdh1);
      const int rp = (b * 64 + rdhc) * 64;
      #pragma unroll
      for (int it = 0; it < 4; ++it) {
        const int s = t + it * 256;
        const int px = s >> 5, co = s & 31;
        const int w = wbase - 8 + px;
        const int wc = w < 0 ? 0 : (w > 63 ? 63 : w);
        const int g = (rp + wc) * 256 + co * 8;
        uint4 vv = *(const uint4*)(vo + g);
        const bool zz = (!rok2) | (w < 0) | (w > 63);
        pv[it].x = zz ? 0u : vv.x; pv[it].y = zz ? 0u : vv.y; pv[it].z = zz ? 0u : vv.z; pv[it].w = zz ? 0u : vv.w;
      }
    }
    __syncthreads();                      // tile visible
    #pragma unroll
    for (int i = 0; i < 4; ++i) {
      const int c = wv * 64 + i * 16 + l15;      // A: m = channel
      short8 af;
      u16* afp = (u16*)&af;
      #pragma unroll
      for (int e = 0; e < 8; ++e) {              // gather transpose from LDS
        const int px = q4 * 8 + e;               // k-dim = neighbor pixel
        const int off = swzb(px, c >> 3) + (c & 7) * 2;
        afp[e] = *(const u16*)(sk + off);
      }
      const short8 bf_ = *(const short8*)(&pb[dh][l15][q4 * 8]);
      acc[i] = __builtin_amdgcn_mfma_f32_16x16x32_bf16(af, bf_, acc[i], 0, 0, 0);
    }
  }
  #pragma unroll
  for (int i = 0; i < 4; ++i) {
    const int ct = wv * 4 + i;
    // D: row m = channel q4*4+r, col n = pixel l15 -> native [b][c][h][w]
    #pragma unroll
    for (int r = 0; r < 4; ++r)
      out[(b * 256 + ct * 16 + q4 * 4 + r) * 4096 + h * 64 + wbase + l15] = acc[i][r];
  }
}

extern "C" void kernel_launch(void* const* d_in, const int* in_sizes, int n_in,
                              void* d_out, int out_size, void* d_ws, size_t ws_size,
                              hipStream_t stream)
{
  const float* x  = (const float*)d_in[0];
  const float* w1 = (const float*)d_in[1];
  const float* w2 = (const float*)d_in[2];
  const float* w3 = (const float*)d_in[3];
  float* out = (float*)d_out;

  // x hi/lo bf16 split lives in d_out (16 MB); consumed by qkv_gemm, then d_out is
  // fully rewritten by attn phase 2 (stream-ordered).
  u16* XTh = (u16*)d_out;
  u16* XTl = XTh + 4194304;

  char* ws = (char*)d_ws;
  u16* qh_ = (u16*)ws;                     // 8 MB bf16 hi(q), pixel-major [pix][c]
  u16* ql_ = (u16*)(ws + (8u  << 20));     // 8 MB bf16 lo(q)
  u16* kh_ = (u16*)(ws + (16u << 20));     // 8 MB bf16 hi(k)
  u16* kl_ = (u16*)(ws + (24u << 20));     // 8 MB bf16 lo(k)
  u16* vo  = (u16*)(ws + (32u << 20));     // 8 MB bf16 v, pixel-major [pix][c]
  u16* Wh  = (u16*)(ws + (40u << 20));     // 384 KB
  u16* Wl  = Wh + 196608;                  // 384 KB

  split_in<<<dim3(64, 4, 4), 256, 0, stream>>>(x, XTh, XTl);
  wsplit<<<192, 256, 0, stream>>>(w1, w2, w3, Wh, Wl);
  qkv_gemm<<<dim3(256), 1024, 0, stream>>>(XTh, XTl, Wh, Wl, qh_, ql_, kh_, kl_, vo);
  attn<<<dim3(1024), 256, 0, stream>>>(qh_, ql_, kh_, kl_, vo, out);
}

// Round 8
// 128.959 us; speedup vs baseline: 1.2310x; 1.0871x over previous
//
#include <hip/hip_runtime.h>

typedef unsigned short u16;
typedef unsigned int u32;
typedef __attribute__((ext_vector_type(8))) short short8;
typedef __attribute__((ext_vector_type(4))) float f32x4;

__device__ __forceinline__ float bf2f(u16 h){ return __builtin_bit_cast(float, ((u32)h) << 16); }
__device__ __forceinline__ u16 f2bf(float f){
  u32 u = __builtin_bit_cast(u32, f);
  u32 r = u + 0x7fffu + ((u >> 16) & 1u);
  return (u16)(r >> 16);
}
// byte offset of channel-octet `co` of tile-pixel `px` in a swizzled [px][256ch] bf16 LDS tile
__device__ __forceinline__ int swzb(int px, int co){
  return px * 512 + ((co * 16) ^ ((((px & 7) ^ ((px >> 3) * 3)) & 7) << 4));
}

// ------- Kernel 0: x fp32 [b][c][hw] -> XTh/XTl bf16 hi/lo split, pixel-major [pix][c] -------
__global__ __launch_bounds__(256) void split_in(const float* __restrict__ x,
                                                u16* __restrict__ XTh,
                                                u16* __restrict__ XTl)
{
  __shared__ float tile[64 * 68];
  int t = threadIdx.x;
  int hw0 = blockIdx.x * 64, c0 = blockIdx.y * 64, b = blockIdx.z;
  {
    int cl = t >> 2, seg = (t & 3) * 16;
    const float* src = x + (b * 256 + c0 + cl) * 4096 + hw0 + seg;
    float4 v0 = ((const float4*)src)[0];
    float4 v1 = ((const float4*)src)[1];
    float4 v2 = ((const float4*)src)[2];
    float4 v3 = ((const float4*)src)[3];
    float* d = tile + cl * 68 + seg;
    ((float4*)d)[0] = v0; ((float4*)d)[1] = v1;
    ((float4*)d)[2] = v2; ((float4*)d)[3] = v3;
  }
  __syncthreads();
  {
    int hwl = t >> 2, cs = (t & 3) * 16;
    u32 ph[8], pl[8];
    #pragma unroll
    for (int e = 0; e < 8; ++e) {
      float v0 = tile[(cs + 2 * e) * 68 + hwl];
      float v1 = tile[(cs + 2 * e + 1) * 68 + hwl];
      u16 h0 = f2bf(v0), h1 = f2bf(v1);
      u16 l0 = f2bf(v0 - bf2f(h0)), l1 = f2bf(v1 - bf2f(h1));
      ph[e] = (u32)h0 | ((u32)h1 << 16);
      pl[e] = (u32)l0 | ((u32)l1 << 16);
    }
    int off = (b * 4096 + hw0 + hwl) * 256 + c0 + cs;
    *(uint4*)(XTh + off)     = make_uint4(ph[0], ph[1], ph[2], ph[3]);
    *(uint4*)(XTh + off + 8) = make_uint4(ph[4], ph[5], ph[6], ph[7]);
    *(uint4*)(XTl + off)     = make_uint4(pl[0], pl[1], pl[2], pl[3]);
    *(uint4*)(XTl + off + 8) = make_uint4(pl[4], pl[5], pl[6], pl[7]);
  }
}

// ------- Kernel 0b: w1|w2|w3 fp32 [o][c] -> Wh/Wl bf16 hi/lo -------
__global__ __launch_bounds__(256) void wsplit(const float* __restrict__ w1,
                                              const float* __restrict__ w2,
                                              const float* __restrict__ w3,
                                              u16* __restrict__ Wh,
                                              u16* __restrict__ Wl)
{
  int i = (blockIdx.x * 256 + threadIdx.x) * 4;
  int z = i >> 16, off = i & 65535;
  const float* w = (z == 0) ? w1 : ((z == 1) ? w2 : w3);
  float4 v = *(const float4*)(w + off);
  u16 h0 = f2bf(v.x), h1 = f2bf(v.y), h2 = f2bf(v.z), h3 = f2bf(v.w);
  u16 l0 = f2bf(v.x - bf2f(h0)), l1 = f2bf(v.y - bf2f(h1));
  u16 l2 = f2bf(v.z - bf2f(h2)), l3 = f2bf(v.w - bf2f(h3));
  uint2 hv; hv.x = (u32)h0 | ((u32)h1 << 16); hv.y = (u32)h2 | ((u32)h3 << 16);
  uint2 lv; lv.x = (u32)l0 | ((u32)l1 << 16); lv.y = (u32)l2 | ((u32)l3 << 16);
  *(uint2*)(Wh + i) = hv;
  *(uint2*)(Wl + i) = lv;
}

// ------- Kernel 1: q/k via 3-pass split-bf16 MFMA -> hi/lo bf16 pixel-major;
//         v via 1-pass -> bf16 c-major [o][pix]. grid (128, 2, 3). (R4 structure:
//         global_load_lds staging, source-chunk XOR involution, linear [128][32] tiles.) -------
__global__ __launch_bounds__(256) void qkv_gemm(const u16* __restrict__ XTh,
                                                const u16* __restrict__ XTl,
                                                const u16* __restrict__ Wh,
                                                const u16* __restrict__ Wl,
                                                u16* __restrict__ qh_, u16* __restrict__ ql_,
                                                u16* __restrict__ kh_, u16* __restrict__ kl_,
                                                u16* __restrict__ vo)
{
  __shared__ u16 lAh[128 * 32];
  __shared__ u16 lBh[128 * 32];
  __shared__ u16 lAl[128 * 32];
  __shared__ u16 lBl[128 * 32];
  const int z = blockIdx.z;
  const int t = threadIdx.x;
  const int lane = t & 63, wv = t >> 6;
  const int ln15 = lane & 15, q = lane >> 4;
  const int pix0 = blockIdx.x * 128;
  const int o0 = blockIdx.y * 128;
  const int pw = (wv >> 1) * 64, ow = (wv & 1) * 64;
  f32x4 acc[4][4];
  #pragma unroll
  for (int i = 0; i < 4; ++i)
    #pragma unroll
    for (int j = 0; j < 4; ++j)
      acc[i][j] = (f32x4){0.f, 0.f, 0.f, 0.f};

  const int Lr = lane >> 2;
  const int cswz = (lane & 3) ^ ((lane >> 3) & 3);
  const int r0 = wv * 32 + Lr;          // slice 0 row
  const int r1 = wv * 32 + 16 + Lr;     // slice 1 row
  const int gA0 = (pix0 + r0) * 256 + cswz * 8;
  const int gA1 = (pix0 + r1) * 256 + cswz * 8;
  const int gB0 = z * 65536 + (o0 + r0) * 256 + cswz * 8;
  const int gB1 = z * 65536 + (o0 + r1) * 256 + cswz * 8;
  const int s0 = wv * 1024;             // wave-uniform LDS slice bases (u16 units)
  const int s1 = wv * 1024 + 512;
  const int qsw = (q ^ ((ln15 >> 1) & 3)) * 8;   // read-side chunk swizzle (u16 units)

  for (int kc = 0; kc < 256; kc += 32) {
    __syncthreads();                    // previous K-step done reading LDS
    __builtin_amdgcn_global_load_lds((const u32*)(XTh + gA0 + kc), (u32*)(lAh + s0), 16, 0, 0);
    __builtin_amdgcn_global_load_lds((const u32*)(XTh + gA1 + kc), (u32*)(lAh + s1), 16, 0, 0);
    __builtin_amdgcn_global_load_lds((const u32*)(Wh  + gB0 + kc), (u32*)(lBh + s0), 16, 0, 0);
    __builtin_amdgcn_global_load_lds((const u32*)(Wh  + gB1 + kc), (u32*)(lBh + s1), 16, 0, 0);
    if (z < 2) {
      __builtin_amdgcn_global_load_lds((const u32*)(XTl + gA0 + kc), (u32*)(lAl + s0), 16, 0, 0);
      __builtin_amdgcn_global_load_lds((const u32*)(XTl + gA1 + kc), (u32*)(lAl + s1), 16, 0, 0);
      __builtin_amdgcn_global_load_lds((const u32*)(Wl  + gB0 + kc), (u32*)(lBl + s0), 16, 0, 0);
      __builtin_amdgcn_global_load_lds((const u32*)(Wl  + gB1 + kc), (u32*)(lBl + s1), 16, 0, 0);
    }
    __syncthreads();                    // vmcnt drained at barrier -> tiles visible
    short8 afh[4], bfh[4];
    #pragma unroll
    for (int i = 0; i < 4; ++i)
      afh[i] = *(const short8*)(lAh + (pw + i * 16 + ln15) * 32 + qsw);
    #pragma unroll
    for (int j = 0; j < 4; ++j)
      bfh[j] = *(const short8*)(lBh + (ow + j * 16 + ln15) * 32 + qsw);
    #pragma unroll
    for (int i = 0; i < 4; ++i)
      #pragma unroll
      for (int j = 0; j < 4; ++j)
        acc[i][j] = __builtin_amdgcn_mfma_f32_16x16x32_bf16(afh[i], bfh[j], acc[i][j], 0, 0, 0);
    if (z < 2) {
      short8 afl[4], bfl[4];
      #pragma unroll
      for (int i = 0; i < 4; ++i)
        afl[i] = *(const short8*)(lAl + (pw + i * 16 + ln15) * 32 + qsw);
      #pragma unroll
      for (int j = 0; j < 4; ++j)
        bfl[j] = *(const short8*)(lBl + (ow + j * 16 + ln15) * 32 + qsw);
      #pragma unroll
      for (int i = 0; i < 4; ++i)
        #pragma unroll
        for (int j = 0; j < 4; ++j) {
          acc[i][j] = __builtin_amdgcn_mfma_f32_16x16x32_bf16(afh[i], bfl[j], acc[i][j], 0, 0, 0);
          acc[i][j] = __builtin_amdgcn_mfma_f32_16x16x32_bf16(afl[i], bfh[j], acc[i][j], 0, 0, 0);
        }
    }
  }

  // D: m(pixel) = pw + i*16 + q*4 + r, n(o) = ow + j*16 + ln15
  if (z == 2) {
    // v: c-major [o][pix]; 4 acc regs = 4 consecutive pixels -> packed uint2 store
    #pragma unroll
    for (int i = 0; i < 4; ++i) {
      int pixb = pix0 + pw + i * 16 + q * 4;
      #pragma unroll
      for (int j = 0; j < 4; ++j) {
        int o = o0 + ow + j * 16 + ln15;
        u32 p0 = (u32)f2bf(acc[i][j][0]) | ((u32)f2bf(acc[i][j][1]) << 16);
        u32 p1 = (u32)f2bf(acc[i][j][2]) | ((u32)f2bf(acc[i][j][3]) << 16);
        uint2 pvv; pvv.x = p0; pvv.y = p1;
        *(uint2*)(vo + o * 16384 + pixb) = pvv;
      }
    }
  } else {
    u16* dsth = (z == 0) ? qh_ : kh_;
    u16* dstl = (z == 0) ? ql_ : kl_;
    #pragma unroll
    for (int i = 0; i < 4; ++i) {
      #pragma unroll
      for (int r = 0; r < 4; ++r) {
        int pix = pix0 + pw + i * 16 + q * 4 + r;
        int ob = o0 + ow + ln15;
        #pragma unroll
        for (int j = 0; j < 4; ++j) {
          float vv = acc[i][j][r];
          u16 hh = f2bf(vv);
          u16 ll = f2bf(vv - bf2f(hh));
          dsth[pix * 256 + ob + j * 16] = hh;
          dstl[pix * 256 + ob + j * 16] = ll;
        }
      }
    }
  }
}

// ------- Kernel 2: banded-MFMA local attention. Block = quarter row (16 q-px).
// Phase 1 unchanged (k pixel-major swzb tiles). Phase 2: V is c-major in global
// ([o][pix]); per-dh LDS tile [256c][32px] with px-octet XOR swizzle po^=(c&3)^((c>>2)&3)
// -> A-fragment is ONE ds_read_b128 (was 8x ds_read_u16 gather). OOB masked per-octet
// at staging (octet boundaries align with w-validity since wbase % 16 == 0). -------
__global__ __launch_bounds__(256, 4) void attn(const u16* __restrict__ qh_,
                                               const u16* __restrict__ ql_,
                                               const u16* __restrict__ kh_,
                                               const u16* __restrict__ kl_,
                                               const u16* __restrict__ vo,
                                               float* __restrict__ out)
{
  __shared__ u16 kst[12288];             // 24576 B: k hi @0, k lo @+12288B; q @0/+8192B; v tile @0 (16 KB)
  __shared__ float lg2[2][16][57];       // 7296 B
  __shared__ u16 pb[7][16][40];          // 8960 B   (total 40832 <= 40960 -> 4 blocks/CU)

  const int t = threadIdx.x;
  const int lane = t & 63, wv = t >> 6;
  const int l15 = lane & 15, q4 = lane >> 4;
  const int bid = ((int)blockIdx.x & 7) * 128 + ((int)blockIdx.x >> 3);  // XCD-bijective
  const int quarter = bid & 3;
  const int row = bid >> 2;               // b*64 + h
  const int b = row >> 6, h = row & 63;
  const int wbase = quarter * 16;
  char* sk = (char*)kst;

  for (int i = t; i < 2 * 16 * 57; i += 256) ((float*)lg2)[i] = 0.f;
  for (int i = t; i < 2240; i += 256) ((u32*)pb)[i] = 0u;

  // ---------- q stage (coalesced 16 KB) ----------
  #pragma unroll
  for (int it = 0; it < 2; ++it) {
    const int s = t + it * 256;                 // 0..511
    const int px = s >> 5, co = s & 31;
    const int g = (row * 64 + wbase + px) * 256 + co * 8;
    const uint4 vh = *(const uint4*)(qh_ + g);
    const uint4 vl = *(const uint4*)(ql_ + g);
    const int off = swzb(px, co);
    *(uint4*)(sk + off) = vh;
    *(uint4*)(sk + 8192 + off) = vl;
  }

  const int ch = wv >> 1, win = wv & 1;          // wave -> (c-half, n-window)
  uint4 ph[3], pl[3];
  // k prefetch for dh=0 (flies during barrier + q-frag reads)
  {
    const int rdh0 = h - 3;
    const int rdhc = rdh0 < 0 ? 0 : rdh0;
    const int rp = (b * 64 + rdhc) * 64;
    #pragma unroll
    for (int it = 0; it < 3; ++it) {
      const int s = t + it * 256;
      const int px = s >> 5, co = s & 31;
      const int w = wbase - 4 + px;
      const int wc = w < 0 ? 0 : (w > 63 ? 63 : w);
      const int g = (rp + wc) * 256 + co * 8;
      uint4 vh = *(const uint4*)(kh_ + g);
      uint4 vl = *(const uint4*)(kl_ + g);
      const bool zz = (w < 0) | (w > 63);
      ph[it].x = zz ? 0u : vh.x; ph[it].y = zz ? 0u : vh.y; ph[it].z = zz ? 0u : vh.z; ph[it].w = zz ? 0u : vh.w;
      pl[it].x = zz ? 0u : vl.x; pl[it].y = zz ? 0u : vl.y; pl[it].z = zz ? 0u : vl.z; pl[it].w = zz ? 0u : vl.w;
    }
  }
  __syncthreads();

  // q fragments from LDS
  short8 qfh[4], qfl[4];
  #pragma unroll
  for (int u = 0; u < 4; ++u) {
    const int co = (ch * 4 + u) * 4 + q4;
    const int off = swzb(l15, co);
    qfh[u] = *(const short8*)(sk + off);
    qfl[u] = *(const short8*)(sk + 8192 + off);
  }

  // ---------- phase 1: logits ----------
  const int tidx = win ? (l15 + 12 > 23 ? 23 : l15 + 12) : (l15 - 4 < 0 ? 0 : l15 - 4);
  #pragma unroll 1
  for (int dh = 0; dh < 7; ++dh) {
    __syncthreads();                      // previous compute done reading kst
    #pragma unroll
    for (int it = 0; it < 3; ++it) {      // WRITEK
      const int s = t + it * 256;
      const int px = s >> 5, co = s & 31;
      const int off = swzb(px, co);
      *(uint4*)(sk + off) = ph[it];
      *(uint4*)(sk + 12288 + off) = pl[it];
    }
    if (dh < 6) {                         // LOADK(dh+1): flies during compute
      const int rdh1 = h + dh - 2;
      const int rdhc = rdh1 < 0 ? 0 : (rdh1 > 63 ? 63 : rdh1);
      const int rp = (b * 64 + rdhc) * 64;
      #pragma unroll
      for (int it = 0; it < 3; ++it) {
        const int s = t + it * 256;
        const int px = s >> 5, co = s & 31;
        const int w = wbase - 4 + px;
        const int wc = w < 0 ? 0 : (w > 63 ? 63 : w);
        const int g = (rp + wc) * 256 + co * 8;
        uint4 vh = *(const uint4*)(kh_ + g);
        uint4 vl = *(const uint4*)(kl_ + g);
        const bool zz = (w < 0) | (w > 63);
        ph[it].x = zz ? 0u : vh.x; ph[it].y = zz ? 0u : vh.y; ph[it].z = zz ? 0u : vh.z; ph[it].w = zz ? 0u : vh.w;
        pl[it].x = zz ? 0u : vl.x; pl[it].y = zz ? 0u : vl.y; pl[it].z = zz ? 0u : vl.z; pl[it].w = zz ? 0u : vl.w;
      }
    }
    __syncthreads();                      // staged tile visible
    const int rdh = h + dh - 3;
    const bool rok = (rdh >= 0) && (rdh < 64);
    f32x4 a0 = {0.f, 0.f, 0.f, 0.f};
    f32x4 a1 = {0.f, 0.f, 0.f, 0.f};     // split chains for MFMA ILP
    #pragma unroll
    for (int u = 0; u < 4; ++u) {
      const int co = (ch * 4 + u) * 4 + q4;
      const int off = swzb(tidx, co);
      const short8 bh_ = *(const short8*)(sk + off);
      const short8 bl_ = *(const short8*)(sk + 12288 + off);
      a0 = __builtin_amdgcn_mfma_f32_16x16x32_bf16(qfh[u], bh_, a0, 0, 0, 0);
      a1 = __builtin_amdgcn_mfma_f32_16x16x32_bf16(qfh[u], bl_, a1, 0, 0, 0);
      a0 = __builtin_amdgcn_mfma_f32_16x16x32_bf16(qfl[u], bh_, a0, 0, 0, 0);
    }
    // scatter band entries: D col n=l15, row m=q4*4+r; dw = n_w - m_w + 3
    #pragma unroll
    for (int r = 0; r < 4; ++r) {
      const int mloc = q4 * 4 + r;
      const int dw = l15 - mloc - 5 + win * 16;
      if (rok && dw >= 0 && dw < 7) lg2[ch][mloc][dh * 7 + dw] = a0[r] + a1[r];
    }
  }

  // v prefetch for dh=0 (c-major vo[o*16384+pix]; flies during softmax)
  uint4 pv[4];
  {
    const int rdh0 = h - 3;
    const bool rok2 = rdh0 >= 0;
    const int rdhc = rdh0 < 0 ? 0 : rdh0;
    const int rp = (b * 64 + rdhc) * 64;
    #pragma unroll
    for (int it = 0; it < 4; ++it) {
      const int s = t + it * 256;                // 0..1023
      const int c = s >> 2, po = s & 3;          // channel, px-octet
      const int w0 = wbase - 8 + po * 8;
      const int wc = w0 < 0 ? 0 : (w0 > 56 ? 56 : w0);
      const int g = c * 16384 + rp + wc;
      uint4 vv = *(const uint4*)(vo + g);
      const bool zz = (!rok2) | (w0 < 0) | (w0 > 56);
      pv[it].x = zz ? 0u : vv.x; pv[it].y = zz ? 0u : vv.y; pv[it].z = zz ? 0u : vv.z; pv[it].w = zz ? 0u : vv.w;
    }
  }
  __syncthreads();

  // ---------- softmax: 16 lanes per pixel ----------
  {
    const int px = t >> 4, sub = t & 15;
    float mx = -3.0e38f;
    for (int i = sub; i < 49; i += 16)
      mx = fmaxf(mx, lg2[0][px][i] + lg2[1][px][i]);
    mx = fmaxf(mx, __shfl_xor(mx, 1));
    mx = fmaxf(mx, __shfl_xor(mx, 2));
    mx = fmaxf(mx, __shfl_xor(mx, 4));
    mx = fmaxf(mx, __shfl_xor(mx, 8));
    float s = 0.f;
    for (int i = sub; i < 49; i += 16) {
      float v = __expf(lg2[0][px][i] + lg2[1][px][i] - mx);
      lg2[0][px][i] = v;                  // stash exp (same-lane RAW only)
      s += v;
    }
    s += __shfl_xor(s, 1);
    s += __shfl_xor(s, 2);
    s += __shfl_xor(s, 4);
    s += __shfl_xor(s, 8);
    const float inv = 1.f / s;
    for (int i = sub; i < 49; i += 16) {
      const int dh7 = i / 7, dw7 = i - dh7 * 7;
      pb[dh7][px][px + 5 + dw7] = f2bf(lg2[0][px][i] * inv);
    }
  }

  // ---------- phase 2: out[c][m'] = sum_n' v[c][n'] * P[m'][n'] ----------
  // LDS v tile: byte off = c*64 + ((po ^ ((c&3)^((c>>2)&3)))*16) + (px&7)*2
  f32x4 acc[4];
  #pragma unroll
  for (int i = 0; i < 4; ++i) acc[i] = (f32x4){0.f, 0.f, 0.f, 0.f};
  #pragma unroll 1
  for (int dh = 0; dh < 7; ++dh) {
    __syncthreads();                      // kst free (phase1 / prev iter done)
    #pragma unroll
    for (int it = 0; it < 4; ++it) {      // WRITEV (swizzled c-major tile)
      const int s = t + it * 256;
      const int c = s >> 2, po = s & 3;
      const int sc = (c & 3) ^ ((c >> 2) & 3);
      *(uint4*)(sk + c * 64 + ((po ^ sc) * 16)) = pv[it];
    }
    if (dh < 6) {                         // LOADV(dh+1)
      const int rdh1 = h + dh - 2;
      const bool rok2 = (rdh1 >= 0) && (rdh1 < 64);
      const int rdhc = rdh1 < 0 ? 0 : (rdh1 > 63 ? 63 : rdh1);
      const int rp = (b * 64 + rdhc) * 64;
      #pragma unroll
      for (int it = 0; it < 4; ++it) {
        const int s = t + it * 256;
        const int c = s >> 2, po = s & 3;
        const int w0 = wbase - 8 + po * 8;
        const int wc = w0 < 0 ? 0 : (w0 > 56 ? 56 : w0);
        const int g = c * 16384 + rp + wc;
        uint4 vv = *(const uint4*)(vo + g);
        const bool zz = (!rok2) | (w0 < 0) | (w0 > 56);
        pv[it].x = zz ? 0u : vv.x; pv[it].y = zz ? 0u : vv.y; pv[it].z = zz ? 0u : vv.z; pv[it].w = zz ? 0u : vv.w;
      }
    }
    __syncthreads();                      // tile visible
    #pragma unroll
    for (int i = 0; i < 4; ++i) {
      const int c = wv * 64 + i * 16 + l15;      // A: m = channel, k-octet = q4
      const int sc = (c & 3) ^ ((c >> 2) & 3);
      const short8 af = *(const short8*)(sk + c * 64 + ((q4 ^ sc) * 16));
      const short8 bf_ = *(const short8*)(&pb[dh][l15][q4 * 8]);
      acc[i] = __builtin_amdgcn_mfma_f32_16x16x32_bf16(af, bf_, acc[i], 0, 0, 0);
    }
  }
  #pragma unroll
  for (int i = 0; i < 4; ++i) {
    const int ct = wv * 4 + i;
    // D: row m = channel q4*4+r, col n = pixel l15 -> native [b][c][h][w]
    #pragma unroll
    for (int r = 0; r < 4; ++r)
      out[(b * 256 + ct * 16 + q4 * 4 + r) * 4096 + h * 64 + wbase + l15] = acc[i][r];
  }
}

extern "C" void kernel_launch(void* const* d_in, const int* in_sizes, int n_in,
                              void* d_out, int out_size, void* d_ws, size_t ws_size,
                              hipStream_t stream)
{
  const float* x  = (const float*)d_in[0];
  const float* w1 = (const float*)d_in[1];
  const float* w2 = (const float*)d_in[2];
  const float* w3 = (const float*)d_in[3];
  float* out = (float*)d_out;

  // x hi/lo bf16 split lives in d_out (16 MB); consumed by qkv_gemm, then d_out is
  // fully rewritten by attn phase 2 (stream-ordered).
  u16* XTh = (u16*)d_out;
  u16* XTl = XTh + 4194304;

  char* ws = (char*)d_ws;
  u16* qh_ = (u16*)ws;                     // 8 MB bf16 hi(q), pixel-major [pix][c]
  u16* ql_ = (u16*)(ws + (8u  << 20));     // 8 MB bf16 lo(q)
  u16* kh_ = (u16*)(ws + (16u << 20));     // 8 MB bf16 hi(k)
  u16* kl_ = (u16*)(ws + (24u << 20));     // 8 MB bf16 lo(k)
  u16* vo  = (u16*)(ws + (32u << 20));     // 8 MB bf16 v, c-major [o][pix]
  u16* Wh  = (u16*)(ws + (40u << 20));     // 384 KB
  u16* Wl  = Wh + 196608;                  // 384 KB

  split_in<<<dim3(64, 4, 4), 256, 0, stream>>>(x, XTh, XTl);
  wsplit<<<192, 256, 0, stream>>>(w1, w2, w3, Wh, Wl);
  qkv_gemm<<<dim3(128, 2, 3), 256, 0, stream>>>(XTh, XTl, Wh, Wl, qh_, ql_, kh_, kl_, vo);
  attn<<<dim3(1024), 256, 0, stream>>>(qh_, ql_, kh_, kl_, vo, out);
}